// Round 5
// baseline (912.151 us; speedup 1.0000x reference)
//
#include <hip/hip_runtime.h>

// CTC batch cost (Keras ctc_batch_cost, full lengths).
// B=64, T=2048, C=128 (blank=127), L=256, S=513.
//
// Round-5: single-wave structure (Round 4) + log2-domain LSE (Round 3's
// verified numerics). Linear-domain w/ wave-global renorm (Round 4) FAILED:
// f32's ~190-nat dynamic range can't hold the CTC alpha vector, whose spread
// across states reaches hundreds of nats -> end-path mass flushed to zero.
//
// One wave (64 lanes) per batch element -> no barrier, no LDS. Lane l owns
// states 8l..8l+7 in registers (lane 63 also owns state 512). Only cross-lane
// term per step: left neighbor's a7 -> one __shfl_up (verified in Round 3).
// No __syncthreads() -> compiler keeps prefetch loads in flight with
// fine-grained vmcnt(N) (Round 3's per-step barrier forced vmcnt(0) drains).
//
// All LSE math in log2 domain (v_exp_f32 / v_log_f32 are base-2 native);
// known-max trick (max/med3/min, exp2(0)=1): lse2 = 1 exp + 1 log,
// lse3 = 2 exp + 1 log. y_pred gathers (5 dwords/lane/step) prefetched
// PF_=8 rows ahead in a register circular buffer (~2000 cy of cover).

#define B_ 64
#define T_ 2048
#define C_ 128
#define L_ 256
#define BLANK_ (C_ - 1)
#define NEGF (-1e30f)
#define EPSF 1e-7f
#define LN2F 0.69314718055994530942f
#define PF_ 8

__launch_bounds__(64, 1)
__global__ void ctc_loss_kernel(const int* __restrict__ y_true,
                                const float* __restrict__ y_pred,
                                float* __restrict__ out) {
    const int b = blockIdx.x;
    const int l = threadIdx.x;  // 0..63

    const int* __restrict__ lab = y_true + b * L_;
    const int i0 = 4 * l;
    const int4 lv = *(const int4*)(lab + i0);   // labels 4l..4l+3 (16B aligned)
    const int e1 = lv.x, e3 = lv.y, e5 = lv.z, e7 = lv.w;
    const int em1 = (l > 0) ? lab[i0 - 1] : -1;
    const bool k1 = (l > 0) && (e1 != em1);     // skip flags for odd states
    const bool k3 = (e3 != e1);
    const bool k5 = (e5 != e3);
    const bool k7 = (e7 != e5);
    const bool is63 = (l == 63);

    const float* __restrict__ base = y_pred + (size_t)b * (T_ * C_);

    // Register circular prefetch: 5 gathered dwords per row, PF_ rows deep.
    float qb[PF_], q1[PF_], q3[PF_], q5[PF_], q7[PF_];
#pragma unroll
    for (int r = 0; r < PF_; ++r) {
        const float* __restrict__ row = base + r * C_;
        qb[r] = row[BLANK_]; q1[r] = row[e1]; q3[r] = row[e3];
        q5[r] = row[e5];     q7[r] = row[e7];
    }

    // alphas (log2 domain): states 8l..8l+7 in a0..a7; a8 = state 512 (lane63).
    float a0, a1, a2, a3, a4, a5, a6, a7, a8;
    a0 = (l == 0) ? __log2f(qb[0] + EPSF) : NEGF;  // state 0 (blank) @ t=0
    a1 = (l == 0) ? __log2f(q1[0] + EPSF) : NEGF;  // state 1 (label 0) @ t=0
    a2 = a3 = a4 = a5 = a6 = a7 = a8 = NEGF;
    {   // refill slot 0 with row PF_
        const float* __restrict__ row = base + PF_ * C_;
        qb[0] = row[BLANK_]; q1[0] = row[e1]; q3[0] = row[e3];
        q5[0] = row[e5];     q7[0] = row[e7];
    }

    // NEG is finite -> differences never produce NaN; exp2(-huge) = 0.
    auto lse2 = [](float x, float y) {
        const float m = fmaxf(x, y), w = fminf(x, y);
        return m + __log2f(1.0f + exp2f(w - m));
    };
    auto lse3 = [](float x, float y, float z) {
        const float m = fmaxf(fmaxf(x, y), z);
        const float p = __builtin_amdgcn_fmed3f(x, y, z);
        const float w = fminf(fminf(x, y), z);
        return m + __log2f(1.0f + exp2f(p - m) + exp2f(w - m));
    };

    auto step = [&](const int R, const int t) {
        // lp for this step (loads were issued PF_ steps ago)
        const float lpb = __log2f(qb[R] + EPSF);
        const float lp1 = __log2f(q1[R] + EPSF);
        const float lp3 = __log2f(q3[R] + EPSF);
        const float lp5 = __log2f(q5[R] + EPSF);
        const float lp7 = __log2f(q7[R] + EPSF);
        // refill slot R with row t+PF_ (clamped; tail refills go unread)
        int tn = t + PF_; if (tn > T_ - 1) tn = T_ - 1;
        const float* __restrict__ row = base + (size_t)tn * C_;
        qb[R] = row[BLANK_]; q1[R] = row[e1]; q3[R] = row[e3];
        q5[R] = row[e5];     q7[R] = row[e7];

        float up = __shfl_up(a7, 1);            // state 8l-1 from left neighbor
        if (l == 0) up = NEGF;

        const float n0 = lse2(a0, up) + lpb;                  // even (blank)
        const float n1 = lse3(a1, a0, k1 ? up : NEGF) + lp1;  // odd
        const float n2 = lse2(a2, a1) + lpb;
        const float n3 = lse3(a3, a2, k3 ? a1 : NEGF) + lp3;
        const float n4 = lse2(a4, a3) + lpb;
        const float n5 = lse3(a5, a4, k5 ? a3 : NEGF) + lp5;
        const float n6 = lse2(a6, a5) + lpb;
        const float n7 = lse3(a7, a6, k7 ? a5 : NEGF) + lp7;
        const float n8 = lse2(a8, is63 ? a7 : NEGF) + lpb;    // state 512
        a0 = n0; a1 = n1; a2 = n2; a3 = n3; a4 = n4;
        a5 = n5; a6 = n6; a7 = n7; a8 = n8;
    };

    // Peel: t = 1..7 (slot t holds row t; refills rows 9..15).
#pragma unroll
    for (int t = 1; t < PF_; ++t) step(t, t);

    // Main: t = 8..2047 in chunks of 8 so slot index R = t&7 constant-folds.
    for (int tb = PF_; tb < T_; tb += PF_) {
#pragma unroll
        for (int j = 0; j < PF_; ++j) step(j, tb + j);
    }

    if (is63) {
        // loss = -logaddexp(alpha[512], alpha[511]) (natural log)
        out[b] = -LN2F * lse2(a7, a8);
    }
}

extern "C" void kernel_launch(void* const* d_in, const int* in_sizes, int n_in,
                              void* d_out, int out_size, void* d_ws, size_t ws_size,
                              hipStream_t stream) {
    const int* y_true = (const int*)d_in[0];
    const float* y_pred = (const float*)d_in[1];
    float* out = (float*)d_out;
    ctc_loss_kernel<<<B_, 64, 0, stream>>>(y_true, y_pred, out);
}

// Round 6
// 379.843 us; speedup vs baseline: 2.4014x; 2.4014x over previous
//
#include <hip/hip_runtime.h>

// CTC batch cost (Keras ctc_batch_cost, full lengths).
// B=64, T=2048, C=128 (blank=127), L=256, S=513.
//
// Round-6: single wave per batch element (no barriers, no syncthreads).
// Lane l owns states 8l..8l+7 (+ state 512 on lane 63) in registers.
//
// (a) Staging: y_pred rows go global->LDS via global_load_lds (width 16),
//     16-row chunks (8 insts/chunk), 2-chunk ring, explicit
//     s_waitcnt vmcnt(8) at chunk top: in-order retirement => chunk k landed
//     while chunk k+1 stays in flight. This defeats Round 3/5's failure mode:
//     the compiler refuses to keep a deep register prefetch live
//     (R5 VGPR_Count=40 < the 60+ needed => loads sunk to use => ~900cy/step).
// (b) Numerics: per-lane BLOCK-FLOAT linear domain. A lane's 8 states share
//     int exponent E, renormalized every step with an exact power-of-2 scale
//     (a_i*2^E invariant holds for any extracted e). Cross-lane inflow is
//     rescaled by 2^clamp(upE-Eb,-126,120); an all-zero lane (E==SENT) adopts
//     the neighbor's exponent => first contact exact. Unlike Round 4 (global
//     renorm, 300+ nat spread => flushed real mass), flushing here is vs the
//     8-state LOCAL window (spread ~5-40 nats << 87-nat f32 limit).
//     Zero transcendentals in the loop; one __logf at the end.

#define B_ 64
#define T_ 2048
#define C_ 128
#define L_ 256
#define BLANK_ (C_ - 1)
#define EPSF 1e-7f
#define LN2F 0.69314718055994530942f
#define CH_ 16                // rows per chunk
#define NCH_ (T_ / CH_)       // 128 chunks
#define SENT_ (-(1 << 28))    // "lane is all-zero" exponent sentinel

typedef __attribute__((address_space(1))) const void glob_cv;
typedef __attribute__((address_space(3))) void lds_v;

// One global_load_lds_dwordx4: 64 lanes x 16B = 1024B (two rows).
// LDS dest is wave-uniform base + lane*16 (m104); global addr is per-lane.
__device__ __forceinline__ void gl2lds16(const float* g, float* l) {
    __builtin_amdgcn_global_load_lds((glob_cv*)g, (lds_v*)l, 16, 0, 0);
}

#define WAIT_VM(n) asm volatile("s_waitcnt vmcnt(" #n ")" ::: "memory")

__launch_bounds__(64, 1)
__global__ void ctc_loss_kernel(const int* __restrict__ y_true,
                                const float* __restrict__ y_pred,
                                float* __restrict__ out) {
    const int b = blockIdx.x;
    const int l = threadIdx.x;  // 0..63

    __shared__ float ring[2][CH_ * C_];  // 2 x 16 rows x 128 f32 = 16 KB

    const int* __restrict__ lab = y_true + b * L_;
    const int4 lv = *(const int4*)(lab + 4 * l);   // labels 4l..4l+3
    const int e1 = lv.x, e3 = lv.y, e5 = lv.z, e7 = lv.w;
    const int em1 = (l > 0) ? lab[4 * l - 1] : -1;
    // skip multipliers as floats (uniform over time -> fold into fma)
    const float m1f = ((l > 0) && (e1 != em1)) ? 1.0f : 0.0f;
    const float m3f = (e3 != e1) ? 1.0f : 0.0f;
    const float m5f = (e5 != e3) ? 1.0f : 0.0f;
    const float m7f = (e7 != e5) ? 1.0f : 0.0f;
    const float m8f = (l == 63) ? 1.0f : 0.0f;     // state 512 inflow gate

    const float* __restrict__ base = y_pred + (size_t)b * (T_ * C_);

    auto issue_chunk = [&](int t0, int bufi) {
        const float* g = base + (size_t)t0 * C_ + 4 * l;  // lane*16B
#pragma unroll
        for (int i = 0; i < 8; ++i)
            gl2lds16(g + i * 256, &ring[bufi][i * 256]);
    };

    // state: linear mantissas (lane-local scale 2^E)
    float a0 = 0.f, a1 = 0.f, a2 = 0.f, a3 = 0.f, a4 = 0.f,
          a5 = 0.f, a6 = 0.f, a7 = 0.f, a8 = 0.f;
    int E = SENT_;

    auto step = [&](const float* __restrict__ row) {
        const float pb  = row[BLANK_] + EPSF;
        const float pp1 = row[e1] + EPSF;
        const float pp3 = row[e3] + EPSF;
        const float pp5 = row[e5] + EPSF;
        const float pp7 = row[e7] + EPSF;
        float upv = __shfl_up(a7, 1);      // state 8l-1 mantissa
        int   upE = __shfl_up(E, 1);       // its scale
        if (l == 0) { upv = 0.0f; upE = SENT_; }
        const bool meN = (E == SENT_);     // lane all-zero -> adopt nbr scale
        const int  Eb  = meN ? upE : E;    // base exponent for this step
        int d = upE - Eb;                  // 0 when meN (exact first contact)
        d = min(max(d, -126), 120);
        const float up = upv * __uint_as_float((unsigned)(d + 127) << 23);
        // banded recurrence (all at scale 2^Eb)
        const float n0 = (a0 + up) * pb;
        const float n1 = fmaf(m1f, up, a0 + a1) * pp1;
        const float n2 = (a1 + a2) * pb;
        const float n3 = fmaf(m3f, a1, a2 + a3) * pp3;
        const float n4 = (a3 + a4) * pb;
        const float n5 = fmaf(m5f, a3, a4 + a5) * pp5;
        const float n6 = (a5 + a6) * pb;
        const float n7 = fmaf(m7f, a5, a6 + a7) * pp7;
        const float n8 = fmaf(m8f, a7, a8) * pb;   // state 512
        // exponent-only renorm (exact for ANY extracted e: a_i*2^E invariant)
        float mx = fmaxf(fmaxf(fmaxf(n0, n1), fmaxf(n2, n3)),
                         fmaxf(fmaxf(n4, n5), fmaxf(n6, n7)));
        mx = fmaxf(mx, n8);
        const int e = (int)(__float_as_uint(mx) >> 23) - 127;
        const float s = __uint_as_float((unsigned)(127 - e) << 23);  // 2^-e
        E = (mx == 0.0f) ? SENT_ : (Eb + e);
        a0 = n0 * s; a1 = n1 * s; a2 = n2 * s; a3 = n3 * s; a4 = n4 * s;
        a5 = n5 * s; a6 = n6 * s; a7 = n7 * s; a8 = n8 * s;
    };

    issue_chunk(0, 0);
    issue_chunk(CH_, 1);

    // ---- chunk 0: t=0 init + steps t=1..15 ----
    WAIT_VM(8);                       // chunk 0 landed; chunk 1 in flight
    {
        const float* r0 = &ring[0][0];
        if (l == 0) { a0 = r0[BLANK_] + EPSF; a1 = r0[e1] + EPSF; E = 0; }
    }
#pragma unroll
    for (int j = 1; j < CH_; ++j) step(&ring[0][j * C_]);
    issue_chunk(2 * CH_, 0);

    // ---- chunks 1..126: wait(8), 16 steps, issue k+2 ----
    for (int k = 1; k < NCH_ - 1; ++k) {
        WAIT_VM(8);                   // chunk k landed (in-order retirement)
        const float* __restrict__ cb = ring[k & 1];
#pragma unroll
        for (int j = 0; j < CH_; ++j) step(cb + j * C_);
        if (k + 2 < NCH_) issue_chunk((k + 2) * CH_, k & 1);
    }

    // ---- chunk 127: nothing behind it -> full drain ----
    WAIT_VM(0);
    {
        const float* __restrict__ cb = ring[(NCH_ - 1) & 1];
#pragma unroll
        for (int j = 0; j < CH_; ++j) step(cb + j * C_);
    }

    if (l == 63) {
        // loss = -ln((a511 + a512) * 2^E)
        out[b] = -(__logf(a7 + a8) + (float)E * LN2F);
    }
}

extern "C" void kernel_launch(void* const* d_in, const int* in_sizes, int n_in,
                              void* d_out, int out_size, void* d_ws, size_t ws_size,
                              hipStream_t stream) {
    const int* y_true = (const int*)d_in[0];
    const float* y_pred = (const float*)d_in[1];
    float* out = (float*)d_out;
    ctc_loss_kernel<<<B_, 64, 0, stream>>>(y_true, y_pred, out);
}

// Round 7
// 272.933 us; speedup vs baseline: 3.3420x; 1.3917x over previous
//
#include <hip/hip_runtime.h>

// CTC batch cost (Keras ctc_batch_cost, full lengths).
// B=64, T=2048, C=128 (blank=127), L=256, S=513.
//
// Round-7 = Round-6 staging (global_load_lds 16B, 2-chunk LDS ring, manual
// s_waitcnt vmcnt(8), zero barriers) + a shortened serial chain:
//   (a) cross-lane a7 via DPP wave_shr:1 (VALU, ~4cy, lane0 gets exact 0)
//       instead of __shfl_up (ds_bpermute, ~30cy on the chain every step).
//   (b) renorm every 4 steps, not every step. Window growth <= 3^4 = 2^6.3,
//       so no overflow; per-lane 8-state window spread stays far below the
//       126-bit flush limit (Round 4's failure was the GLOBAL 513-state
//       window, hundreds of nats wide; the local window is ~40-90 bits).
//   (c) all exponent logic hoisted to the window boundary: between renorms
//       every lane's E is constant, so the neighbor rescale 2^(upE-E) is a
//       precomputed constant `upscale`. Frontier advances <= 2 states/step
//       <= 8/window < 9, so a lane cannot both first-receive and export mass
//       within one window -> boundary adoption is exact.
// Zero transcendentals in the loop; one __logf at the end.

#define B_ 64
#define T_ 2048
#define C_ 128
#define L_ 256
#define BLANK_ (C_ - 1)
#define EPSF 1e-7f
#define LN2F 0.69314718055994530942f
#define CH_ 16                // rows per chunk
#define NCH_ (T_ / CH_)       // 128 chunks
#define SENT_ (-(1 << 28))    // "lane is all-zero" exponent sentinel

typedef __attribute__((address_space(1))) const void glob_cv;
typedef __attribute__((address_space(3))) void lds_v;

// One global_load_lds_dwordx4: 64 lanes x 16B = 1024B (two rows).
__device__ __forceinline__ void gl2lds16(const float* g, float* l) {
    __builtin_amdgcn_global_load_lds((glob_cv*)g, (lds_v*)l, 16, 0, 0);
}

#define WAIT_VM(n) asm volatile("s_waitcnt vmcnt(" #n ")" ::: "memory")

// lane l -> value of lane l-1; lane 0 -> 0. DPP ctrl 0x138 = wave_shr:1.
__device__ __forceinline__ float wave_shr1_zero(float x) {
    return __int_as_float(
        __builtin_amdgcn_update_dpp(0, __float_as_int(x), 0x138, 0xf, 0xf, false));
}

__launch_bounds__(64, 1)
__global__ void ctc_loss_kernel(const int* __restrict__ y_true,
                                const float* __restrict__ y_pred,
                                float* __restrict__ out) {
    const int b = blockIdx.x;
    const int l = threadIdx.x;  // 0..63

    __shared__ float ring[2][CH_ * C_];  // 2 x 16 rows x 128 f32 = 16 KB

    const int* __restrict__ lab = y_true + b * L_;
    const int4 lv = *(const int4*)(lab + 4 * l);   // labels 4l..4l+3
    const int e1 = lv.x, e3 = lv.y, e5 = lv.z, e7 = lv.w;
    const int em1 = (l > 0) ? lab[4 * l - 1] : -1;
    const float m1f = ((l > 0) && (e1 != em1)) ? 1.0f : 0.0f;  // skip gates
    const float m3f = (e3 != e1) ? 1.0f : 0.0f;
    const float m5f = (e5 != e3) ? 1.0f : 0.0f;
    const float m7f = (e7 != e5) ? 1.0f : 0.0f;
    const float m8f = (l == 63) ? 1.0f : 0.0f;     // state 512 inflow gate

    const float* __restrict__ base = y_pred + (size_t)b * (T_ * C_);

    auto issue_chunk = [&](int t0, int bufi) {
        const float* g = base + (size_t)t0 * C_ + 4 * l;  // lane*16B
#pragma unroll
        for (int i = 0; i < 8; ++i)
            gl2lds16(g + i * 256, &ring[bufi][i * 256]);
    };

    // linear mantissas at lane-local scale 2^E
    float a0 = 0.f, a1 = 0.f, a2 = 0.f, a3 = 0.f, a4 = 0.f,
          a5 = 0.f, a6 = 0.f, a7 = 0.f, a8 = 0.f;
    int E = SENT_;
    float upscale = 1.0f;  // 2^(E_nbr - E), fixed within a 4-step window

    auto step = [&](const float* __restrict__ row) {
        const float pb  = row[BLANK_] + EPSF;
        const float pp1 = row[e1] + EPSF;
        const float pp3 = row[e3] + EPSF;
        const float pp5 = row[e5] + EPSF;
        const float pp7 = row[e7] + EPSF;
        const float up = wave_shr1_zero(a7) * upscale;  // state 8l-1, rescaled
        const float n0 = (a0 + up) * pb;
        const float n1 = fmaf(m1f, up, a0 + a1) * pp1;
        const float n2 = (a1 + a2) * pb;
        const float n3 = fmaf(m3f, a1, a2 + a3) * pp3;
        const float n4 = (a3 + a4) * pb;
        const float n5 = fmaf(m5f, a3, a4 + a5) * pp5;
        const float n6 = (a5 + a6) * pb;
        const float n7 = fmaf(m7f, a5, a6 + a7) * pp7;
        const float n8 = fmaf(m8f, a7, a8) * pb;        // state 512
        a0 = n0; a1 = n1; a2 = n2; a3 = n3; a4 = n4;
        a5 = n5; a6 = n6; a7 = n7; a8 = n8;
    };

    // Window boundary: exponent-only renorm (exact: a_i*2^E invariant holds
    // for any power-of-2 scale, incl. subnormal mx) + E exchange + upscale.
    auto boundary = [&]() {
        float mx = fmaxf(fmaxf(fmaxf(a0, a1), fmaxf(a2, a3)),
                         fmaxf(fmaxf(a4, a5), fmaxf(a6, a7)));
        mx = fmaxf(mx, a8);
        const bool z = (mx == 0.0f);
        const int e = (int)(__float_as_uint(mx) >> 23) - 127;
        const float s = z ? 1.0f : __uint_as_float((unsigned)(127 - e) << 23);
        a0 *= s; a1 *= s; a2 *= s; a3 *= s; a4 *= s;
        a5 *= s; a6 *= s; a7 *= s; a8 *= s;
        E = z ? SENT_ : (E + e);
        int upE = __shfl_up(E, 1);          // off the critical chain
        if (l == 0) upE = SENT_;
        if (E == SENT_) E = upE;            // adopt neighbor scale (exact)
        int d = upE - E;                    // 0 right after adoption
        d = min(max(d, -126), 120);
        upscale = __uint_as_float((unsigned)(d + 127) << 23);
    };

    issue_chunk(0, 0);
    issue_chunk(CH_, 1);

    // ---- chunk 0: t=0 init + steps t=1..15 ----
    WAIT_VM(8);                       // chunk 0 landed; chunk 1 in flight
    {
        const float* r0 = &ring[0][0];
        if (l == 0) { a0 = r0[BLANK_] + EPSF; a1 = r0[e1] + EPSF; E = 0; }
    }
    boundary();                       // seeds lane1's adoption of E=0
#pragma unroll
    for (int j = 1; j < CH_; ++j) {
        step(&ring[0][j * C_]);
        if ((j & 3) == 3) boundary(); // t = 3,7,11,15
    }
    issue_chunk(2 * CH_, 0);

    // ---- chunks 1..126: wait(8), 16 steps, issue k+2 ----
    for (int k = 1; k < NCH_ - 1; ++k) {
        WAIT_VM(8);                   // chunk k landed (in-order retirement)
        const float* __restrict__ cb = ring[k & 1];
#pragma unroll
        for (int j = 0; j < CH_; ++j) {
            step(cb + j * C_);
            if ((j & 3) == 3) boundary();  // t ≡ 3 (mod 4)
        }
        if (k + 2 < NCH_) issue_chunk((k + 2) * CH_, k & 1);
    }

    // ---- chunk 127: nothing behind it -> full drain ----
    WAIT_VM(0);
    {
        const float* __restrict__ cb = ring[(NCH_ - 1) & 1];
#pragma unroll
        for (int j = 0; j < CH_; ++j) {
            step(cb + j * C_);
            if ((j & 3) == 3) boundary();  // last at t=2047: a's normalized
        }
    }

    if (l == 63) {
        // loss = -ln((a511 + a512) * 2^E)
        out[b] = -(__logf(a7 + a8) + (float)E * LN2F);
    }
}

extern "C" void kernel_launch(void* const* d_in, const int* in_sizes, int n_in,
                              void* d_out, int out_size, void* d_ws, size_t ws_size,
                              hipStream_t stream) {
    const int* y_true = (const int*)d_in[0];
    const float* y_pred = (const float*)d_in[1];
    float* out = (float*)d_out;
    ctc_loss_kernel<<<B_, 64, 0, stream>>>(y_true, y_pred, out);
}

// Round 8
// 269.847 us; speedup vs baseline: 3.3803x; 1.0114x over previous
//
#include <hip/hip_runtime.h>

// CTC batch cost (Keras ctc_batch_cost, full lengths).
// B=64, T=2048, C=128 (blank=127), L=256, S=513.
//
// Round-8 = Round-7 (single wave/block, block-float linear numerics, DPP
// neighbor pass, renorm every 4 steps, global_load_lds staging) + explicit
// 2-step REGISTER lookahead of the 5 LDS gathers. R7's 231 cy/step was
// ds_read latency (~120cy, m117) exposed on the serial chain: the compiler
// would not pipeline LDS gathers across the alpha recurrence. We rotate
// G-structs g0/g1/g2 in the fully-unrolled chunk body so step j's values
// were issued ~2 steps (~150cy) earlier -> lgkmcnt waits become non-blocking.
// Ring deepens to 4 chunks (32 KB LDS) so chunk k+1 is resident during chunk
// k (lookahead crosses chunk boundaries); vmcnt(8) keeps chunk k+2 in
// flight always (never drains to 0 until the last chunk).

#define B_ 64
#define T_ 2048
#define C_ 128
#define L_ 256
#define BLANK_ (C_ - 1)
#define EPSF 1e-7f
#define LN2F 0.69314718055994530942f
#define CH_ 16                // rows per chunk
#define NCH_ (T_ / CH_)       // 128 chunks
#define SENT_ (-(1 << 28))    // "lane is all-zero" exponent sentinel

typedef __attribute__((address_space(1))) const void glob_cv;
typedef __attribute__((address_space(3))) void lds_v;

// One global_load_lds_dwordx4: 64 lanes x 16B = 1024B (two rows).
__device__ __forceinline__ void gl2lds16(const float* g, float* l) {
    __builtin_amdgcn_global_load_lds((glob_cv*)g, (lds_v*)l, 16, 0, 0);
}

#define WAIT_VM(n) asm volatile("s_waitcnt vmcnt(" #n ")" ::: "memory")

// lane l -> value of lane l-1; lane 0 -> 0. DPP ctrl 0x138 = wave_shr:1.
__device__ __forceinline__ float dpp_shr1_f(float x) {
    return __int_as_float(
        __builtin_amdgcn_update_dpp(0, __float_as_int(x), 0x138, 0xf, 0xf, false));
}
__device__ __forceinline__ int dpp_shr1_i(int x) {
    return __builtin_amdgcn_update_dpp(0, x, 0x138, 0xf, 0xf, false);
}

struct G { float pb, p1, p3, p5, p7; };

__launch_bounds__(64, 1)
__global__ void ctc_loss_kernel(const int* __restrict__ y_true,
                                const float* __restrict__ y_pred,
                                float* __restrict__ out) {
    const int b = blockIdx.x;
    const int l = threadIdx.x;  // 0..63

    __shared__ float ring[4][CH_ * C_];  // 4 x 16 rows x 128 f32 = 32 KB

    const int* __restrict__ lab = y_true + b * L_;
    const int4 lv = *(const int4*)(lab + 4 * l);   // labels 4l..4l+3
    const int e1 = lv.x, e3 = lv.y, e5 = lv.z, e7 = lv.w;
    const int em1 = (l > 0) ? lab[4 * l - 1] : -1;
    const float m1f = ((l > 0) && (e1 != em1)) ? 1.0f : 0.0f;  // skip gates
    const float m3f = (e3 != e1) ? 1.0f : 0.0f;
    const float m5f = (e5 != e3) ? 1.0f : 0.0f;
    const float m7f = (e7 != e5) ? 1.0f : 0.0f;
    const float m8f = (l == 63) ? 1.0f : 0.0f;     // state 512 inflow gate

    const float* __restrict__ base = y_pred + (size_t)b * (T_ * C_);

    auto issue_chunk = [&](int t0, int bufi) {
        const float* g = base + (size_t)t0 * C_ + 4 * l;  // lane*16B
#pragma unroll
        for (int i = 0; i < 8; ++i)
            gl2lds16(g + i * 256, &ring[bufi][i * 256]);
    };

    // eps pre-added at gather time (off the alpha chain)
    auto gather = [&](const float* __restrict__ row) -> G {
        G g;
        g.pb = row[BLANK_] + EPSF;
        g.p1 = row[e1] + EPSF;
        g.p3 = row[e3] + EPSF;
        g.p5 = row[e5] + EPSF;
        g.p7 = row[e7] + EPSF;
        return g;
    };

    // linear mantissas at lane-local scale 2^E
    float a0 = 0.f, a1 = 0.f, a2 = 0.f, a3 = 0.f, a4 = 0.f,
          a5 = 0.f, a6 = 0.f, a7 = 0.f, a8 = 0.f;
    int E = SENT_;
    float upscale = 1.0f;  // 2^(E_nbr - E), fixed within a 4-step window
    G g0, g1;              // gathers for the next two steps (rotated)

    auto step = [&](const G& g) {
        const float up = dpp_shr1_f(a7) * upscale;  // state 8l-1, rescaled
        const float n0 = (a0 + up) * g.pb;
        const float n1 = fmaf(m1f, up, a0 + a1) * g.p1;
        const float n2 = (a1 + a2) * g.pb;
        const float n3 = fmaf(m3f, a1, a2 + a3) * g.p3;
        const float n4 = (a3 + a4) * g.pb;
        const float n5 = fmaf(m5f, a3, a4 + a5) * g.p5;
        const float n6 = (a5 + a6) * g.pb;
        const float n7 = fmaf(m7f, a5, a6 + a7) * g.p7;
        const float n8 = fmaf(m8f, a7, a8) * g.pb;  // state 512
        a0 = n0; a1 = n1; a2 = n2; a3 = n3; a4 = n4;
        a5 = n5; a6 = n6; a7 = n7; a8 = n8;
    };

    // Window boundary: exponent-only renorm (exact: a_i*2^E invariant) +
    // E exchange (DPP) + precompute next window's neighbor upscale.
    auto boundary = [&]() {
        float mx = fmaxf(fmaxf(fmaxf(a0, a1), fmaxf(a2, a3)),
                         fmaxf(fmaxf(a4, a5), fmaxf(a6, a7)));
        mx = fmaxf(mx, a8);
        const bool z = (mx == 0.0f);
        const int e = (int)(__float_as_uint(mx) >> 23) - 127;
        const float s = z ? 1.0f : __uint_as_float((unsigned)(127 - e) << 23);
        a0 *= s; a1 *= s; a2 *= s; a3 *= s; a4 *= s;
        a5 *= s; a6 *= s; a7 *= s; a8 *= s;
        E = z ? SENT_ : (E + e);
        int upE = dpp_shr1_i(E);
        if (l == 0) upE = SENT_;
        if (E == SENT_) E = upE;            // adopt neighbor scale (exact)
        int d = upE - E;                    // 0 right after adoption
        d = min(max(d, -126), 120);
        upscale = __uint_as_float((unsigned)(d + 127) << 23);
    };

    // 16 steps with 2-step gather lookahead. cb = this chunk's buffer,
    // nb = next chunk's buffer (resident). jstart: 1 for chunk 0 (t=0 is
    // init). last: suppress prefetch past the end of the final chunk.
    auto run_chunk = [&](const float* __restrict__ cb,
                         const float* __restrict__ nb,
                         int jstart, bool last) {
#pragma unroll
        for (int j = 0; j < CH_; ++j) {
            if (j < 1 && jstart == 1) continue;  // folds at compile time
            G g2{};
            if (j + 2 < CH_)      g2 = gather(cb + (j + 2) * C_);
            else if (!last)       g2 = gather(nb + (j + 2 - CH_) * C_);
            step(g0);
            if ((j & 3) == 3) boundary();
            g0 = g1; g1 = g2;
        }
    };

    issue_chunk(0, 0);
    issue_chunk(CH_, 1);
    issue_chunk(2 * CH_, 2);

    // ---- chunk 0: t=0 init + steps t=1..15 ----
    WAIT_VM(8);                       // chunks 0,1 landed; 2 in flight
    if (l == 0) { a0 = ring[0][BLANK_] + EPSF; a1 = ring[0][e1] + EPSF; E = 0; }
    boundary();                       // seeds lane1's adoption of E
    g0 = gather(&ring[0][1 * C_]);
    g1 = gather(&ring[0][2 * C_]);
    issue_chunk(3 * CH_, 3);
    run_chunk(ring[0], ring[1], 1, false);

    // ---- chunks 1..125: wait(8) -> chunks <=k+1 landed, k+2 in flight ----
    for (int k = 1; k <= 125; ++k) {
        WAIT_VM(8);
        if (k + 3 < NCH_) issue_chunk((k + 3) * CH_, (k + 3) & 3);
        run_chunk(ring[k & 3], ring[(k + 1) & 3], 0, false);
    }

    // ---- chunk 126 (needs 127 resident for lookahead) + chunk 127 ----
    WAIT_VM(0);
    run_chunk(ring[126 & 3], ring[127 & 3], 0, false);
    run_chunk(ring[127 & 3], (const float*)nullptr, 0, true);

    if (l == 63) {
        // loss = -ln((a511 + a512) * 2^E)  (boundary at t=2047 normalized)
        out[b] = -(__logf(a7 + a8) + (float)E * LN2F);
    }
}

extern "C" void kernel_launch(void* const* d_in, const int* in_sizes, int n_in,
                              void* d_out, int out_size, void* d_ws, size_t ws_size,
                              hipStream_t stream) {
    const int* y_true = (const int*)d_in[0];
    const float* y_pred = (const float*)d_in[1];
    float* out = (float*)d_out;
    ctc_loss_kernel<<<B_, 64, 0, stream>>>(y_true, y_pred, out);
}